// Round 7
// baseline (538.296 us; speedup 1.0000x reference)
//
#include <hip/hip_runtime.h>
#include <hip/hip_bf16.h>
#include <math.h>

typedef __bf16 bf16_t;
typedef __bf16 bf16x4 __attribute__((ext_vector_type(4)));
typedef __bf16 bf16x8 __attribute__((ext_vector_type(8)));
typedef float floatx4 __attribute__((ext_vector_type(4)));

#define N_NODES 32768
#define K_CENT  2048
#define D_DIM   512

// ---------------- prep: fp32 row -> bf16 row + sum of squares ----------------
__global__ void prep_rows_kernel(const float* __restrict__ src,
                                 bf16_t* __restrict__ dst,
                                 float* __restrict__ sq) {
  const int w = threadIdx.x >> 6;
  const int l = threadIdx.x & 63;
  const int row = blockIdx.x * 4 + w;
  const float4* s = (const float4*)(src + (size_t)row * D_DIM);
  float4 f0 = s[l];
  float4 f1 = s[64 + l];
  bf16x4 b0 = { (bf16_t)f0.x, (bf16_t)f0.y, (bf16_t)f0.z, (bf16_t)f0.w };
  bf16x4 b1 = { (bf16_t)f1.x, (bf16_t)f1.y, (bf16_t)f1.z, (bf16_t)f1.w };
  bf16x4* d = (bf16x4*)(dst + (size_t)row * D_DIM);
  d[l] = b0;
  d[64 + l] = b1;
  float v = f0.x*f0.x + f0.y*f0.y + f0.z*f0.z + f0.w*f0.w
          + f1.x*f1.x + f1.y*f1.y + f1.z*f1.z + f1.w*f1.w;
  #pragma unroll
  for (int s2 = 32; s2; s2 >>= 1) v += __shfl_xor(v, s2);
  if (l == 0) sq[row] = v;
}

// ---------------- mask sum -> single scalar ----------------
__global__ void mask_sum_kernel(const float* __restrict__ m,
                                float* __restrict__ out, int n) {
  float v = 0.f;
  for (int i = blockIdx.x * blockDim.x + threadIdx.x; i < n;
       i += gridDim.x * blockDim.x)
    v += m[i];
  #pragma unroll
  for (int s = 32; s; s >>= 1) v += __shfl_xor(v, s);
  __shared__ float red[4];
  if ((threadIdx.x & 63) == 0) red[threadIdx.x >> 6] = v;
  __syncthreads();
  if (threadIdx.x == 0) atomicAdd(out, red[0] + red[1] + red[2] + red[3]);
}

// ---------------- GEMM + fused distance epilogue (BARRIER-FREE) ----------------
// Theory: 4 different LDS/barrier schedules all landed at 162-187 us; the
// invariant stage->drain->barrier structure is the bottleneck, not LDS
// conflicts (fixed, 0) or fetch (fixed, 25 MB). D=512 is small enough to
// read MFMA fragments DIRECTLY from global (L2-hot after XCD remap) into
// registers: no LDS, no s_barrier, no vmcnt drains in the K-loop. Every
// wave streams independently; the compiler software-pipelines the 128
// global_load_dwordx4 (immediate offsets s*64B) against 256 MFMAs.
// Intra-block reuse (A shared by 2 waves, B by 2 waves) is caught by L1.
__global__ void __launch_bounds__(256, 3)
gemm_dist_kernel(const bf16_t* __restrict__ A,
                 const bf16_t* __restrict__ B,
                 const float* __restrict__ x2,
                 const float* __restrict__ c2,
                 const float* __restrict__ mask,
                 float* __restrict__ out_node,
                 float* __restrict__ colsum) {
  __shared__ float colbuf[128];   // tiny: epilogue column reduce only

  const int t = threadIdx.x;
  const int w = t >> 6;        // wave 0..3
  const int l = t & 63;
  const int lr = l & 15;       // A-row / B-col within 16x16 tile
  const int hi = l >> 4;       // k-group within 32 (8 elems each)

  // XCD-aware bijective remap: 4096 blocks = 8 XCDs x 512.
  // XCD x owns bm in [x*32,(x+1)*32) x all 16 bn -> A panel hot in one L2
  // (verified: FETCH 140 MB -> 25 MB in Round 2).
  const int wg = (blockIdx.x & 7) * 512 + (blockIdx.x >> 3);
  const int bm = wg >> 4;      // 0..255  (node-row block)
  const int bn = wg & 15;      // 0..15   (centroid block)

  const int wm = (w >> 1) * 64;
  const int wn = (w & 1) * 64;

  floatx4 acc[4][4] = {};

  // per-lane fragment base pointers (same element mapping as the verified
  // LDS version: row = tile + i*16 + lr, k-bytes = s*64 + hi*16)
  const bf16_t* aP[4];
  const bf16_t* bP[4];
  #pragma unroll
  for (int i = 0; i < 4; ++i)
    aP[i] = A + (size_t)(bm * 128 + wm + i * 16 + lr) * D_DIM + hi * 8;
  #pragma unroll
  for (int j = 0; j < 4; ++j)
    bP[j] = B + (size_t)(bn * 128 + wn + j * 16 + lr) * D_DIM + hi * 8;

  // K-loop: 16 steps of 32, fully unrolled; offsets s*32 elems = s*64 B fold
  // into global_load immediate offsets. No synchronization anywhere.
  #pragma unroll
  for (int s = 0; s < 16; ++s) {
    bf16x8 af[4], bfr[4];
    #pragma unroll
    for (int i = 0; i < 4; ++i) af[i] = *(const bf16x8*)(aP[i] + s * 32);
    #pragma unroll
    for (int j = 0; j < 4; ++j) bfr[j] = *(const bf16x8*)(bP[j] + s * 32);
    #pragma unroll
    for (int i = 0; i < 4; ++i) {
      #pragma unroll
      for (int j = 0; j < 4; ++j)
        acc[i][j] = __builtin_amdgcn_mfma_f32_16x16x32_bf16(
            af[i], bfr[j], acc[i][j], 0, 0, 0);
    }
  }

  // ---- epilogue: C/D layout col = lane&15, row = (lane>>4)*4 + reg ----
  const int col0 = bn * 128 + wn;
  float c2v[4];
  #pragma unroll
  for (int j = 0; j < 4; ++j) c2v[j] = c2[col0 + j * 16 + lr];

  float colacc[4] = {0.f, 0.f, 0.f, 0.f};
  #pragma unroll
  for (int i = 0; i < 4; ++i) {
    const int rbase = bm * 128 + wm + i * 16 + hi * 4;
    #pragma unroll
    for (int r = 0; r < 4; ++r) {
      const int row = rbase + r;
      const float xv = x2[row];
      const float mk = mask[row];
      float* orow = out_node + (size_t)row * K_CENT + col0 + lr;
      #pragma unroll
      for (int j = 0; j < 4; ++j) {
        float d2 = xv + c2v[j] - 2.0f * acc[i][j][r];
        float dist = sqrtf(fmaxf(d2, 1e-12f));
        float dm = dist * mk;
        orow[j * 16] = dm;            // plain store: L2 write-combining
        colacc[j] += dm;
      }
    }
  }

  // reduce column partials across the 4 row-groups of the wave
  #pragma unroll
  for (int j = 0; j < 4; ++j) {
    colacc[j] += __shfl_xor(colacc[j], 16);
    colacc[j] += __shfl_xor(colacc[j], 32);
  }
  // block-level reduce in LDS, one atomic per column
  if (w < 2 && l < 16) {
    #pragma unroll
    for (int j = 0; j < 4; ++j) colbuf[wn + j * 16 + l] = colacc[j];
  }
  __syncthreads();
  if (w >= 2 && l < 16) {
    #pragma unroll
    for (int j = 0; j < 4; ++j) colbuf[wn + j * 16 + l] += colacc[j];
  }
  __syncthreads();
  if (t < 128) atomicAdd(&colsum[bn * 128 + t], colbuf[t]);
}

// ---------------- finalize: graph[k] = colsum[k] / masksum ----------------
__global__ void finalize_kernel(const float* __restrict__ colsum,
                                const float* __restrict__ msum,
                                float* __restrict__ out) {
  int k = blockIdx.x * 256 + threadIdx.x;
  out[k] = colsum[k] / msum[0];
}

extern "C" void kernel_launch(void* const* d_in, const int* in_sizes, int n_in,
                              void* d_out, int out_size, void* d_ws, size_t ws_size,
                              hipStream_t stream) {
  const float* node = (const float*)d_in[0];
  const float* mask = (const float*)d_in[1];
  const float* cent = (const float*)d_in[2];
  float* out_graph = (float*)d_out;            // [1, K] first in return order
  float* out_node  = out_graph + K_CENT;       // [1, N, K]

  char* ws = (char*)d_ws;
  size_t off = 0;
  bf16_t* Abf = (bf16_t*)(ws + off); off += (size_t)N_NODES * D_DIM * sizeof(bf16_t);
  bf16_t* Cbf = (bf16_t*)(ws + off); off += (size_t)K_CENT * D_DIM * sizeof(bf16_t);
  float* x2     = (float*)(ws + off); off += (size_t)N_NODES * sizeof(float);
  float* c2     = (float*)(ws + off); off += (size_t)K_CENT * sizeof(float);
  float* colsum = (float*)(ws + off); off += (size_t)K_CENT * sizeof(float);
  float* msum   = (float*)(ws + off); off += sizeof(float);

  hipMemsetAsync(colsum, 0, (K_CENT + 1) * sizeof(float), stream);

  prep_rows_kernel<<<N_NODES / 4, 256, 0, stream>>>(node, Abf, x2);
  prep_rows_kernel<<<K_CENT / 4, 256, 0, stream>>>(cent, Cbf, c2);
  mask_sum_kernel<<<64, 256, 0, stream>>>(mask, msum, N_NODES);
  gemm_dist_kernel<<<4096, 256, 0, stream>>>(
      Abf, Cbf, x2, c2, mask, out_node, colsum);
  finalize_kernel<<<K_CENT / 256, 256, 0, stream>>>(colsum, msum, out_graph);
}

// Round 8
// 394.374 us; speedup vs baseline: 1.3649x; 1.3649x over previous
//
#include <hip/hip_runtime.h>
#include <hip/hip_bf16.h>
#include <math.h>

typedef __bf16 bf16_t;
typedef __bf16 bf16x4 __attribute__((ext_vector_type(4)));
typedef __bf16 bf16x8 __attribute__((ext_vector_type(8)));
typedef float floatx4 __attribute__((ext_vector_type(4)));

#define N_NODES 32768
#define K_CENT  2048
#define D_DIM   512

// ---------------- prep: fp32 row -> bf16 row + sum of squares ----------------
__global__ void prep_rows_kernel(const float* __restrict__ src,
                                 bf16_t* __restrict__ dst,
                                 float* __restrict__ sq) {
  const int w = threadIdx.x >> 6;
  const int l = threadIdx.x & 63;
  const int row = blockIdx.x * 4 + w;
  const float4* s = (const float4*)(src + (size_t)row * D_DIM);
  float4 f0 = s[l];
  float4 f1 = s[64 + l];
  bf16x4 b0 = { (bf16_t)f0.x, (bf16_t)f0.y, (bf16_t)f0.z, (bf16_t)f0.w };
  bf16x4 b1 = { (bf16_t)f1.x, (bf16_t)f1.y, (bf16_t)f1.z, (bf16_t)f1.w };
  bf16x4* d = (bf16x4*)(dst + (size_t)row * D_DIM);
  d[l] = b0;
  d[64 + l] = b1;
  float v = f0.x*f0.x + f0.y*f0.y + f0.z*f0.z + f0.w*f0.w
          + f1.x*f1.x + f1.y*f1.y + f1.z*f1.z + f1.w*f1.w;
  #pragma unroll
  for (int s2 = 32; s2; s2 >>= 1) v += __shfl_xor(v, s2);
  if (l == 0) sq[row] = v;
}

// ---------------- mask sum -> single scalar ----------------
__global__ void mask_sum_kernel(const float* __restrict__ m,
                                float* __restrict__ out, int n) {
  float v = 0.f;
  for (int i = blockIdx.x * blockDim.x + threadIdx.x; i < n;
       i += gridDim.x * blockDim.x)
    v += m[i];
  #pragma unroll
  for (int s = 32; s; s >>= 1) v += __shfl_xor(v, s);
  __shared__ float red[4];
  if ((threadIdx.x & 63) == 0) red[threadIdx.x >> 6] = v;
  __syncthreads();
  if (threadIdx.x == 0) atomicAdd(out, red[0] + red[1] + red[2] + red[3]);
}

// ---------------- async global -> LDS, 16B per lane ----------------
__device__ inline void gld_lds16(const void* g, void* l) {
  __builtin_amdgcn_global_load_lds(
      (__attribute__((address_space(1))) void*)const_cast<void*>(g),
      (__attribute__((address_space(3))) void*)l, 16, 0, 0);
}

// counted-vmcnt gates; "memory" clobber = compiler fence for LDS/global ops
// (protects ring-slot reuse and pins ds_reads on the correct side)
#define S_WAITV3 asm volatile("s_waitcnt vmcnt(3)" ::: "memory")
#define S_WAITV0 asm volatile("s_waitcnt vmcnt(0)" ::: "memory")

// ---------------- GEMM + fused distance epilogue ----------------
// 128(M) x 256(N) tile, BK=32, 8 waves (2M x 4N of 64x64), 512 threads.
// LDS: ring-3 of K-tile buffers (A 8KB + B 16KB per slot = 72 KB total)
// -> 2 blocks/CU resident (cross-block overlap, m114). Pipeline: lead-2
// prefetch, ONE s_barrier + ONE counted vmcnt(3) per K-tile; no full
// drain until the last tile. Swizzle family verified in R2/R4 (conflicts=0).
__global__ void __launch_bounds__(512, 4)
gemm_dist_kernel(const bf16_t* __restrict__ A,
                 const bf16_t* __restrict__ B,
                 const float* __restrict__ x2,
                 const float* __restrict__ c2,
                 const float* __restrict__ mask,
                 float* __restrict__ out_node,
                 float* __restrict__ colsum) {
  // per K-tile: [rows][32 cols] bf16 = 64 B rows = 4 chunks of 16 B.
  // LDS(row, c) holds DATA chunk c ^ ((row>>1)&3); staging pre-swizzles the
  // global source (gld_lds dest stays linear), reads XOR the chunk index.
  __shared__ __align__(16) bf16_t sA[3][128 * 32];
  __shared__ __align__(16) bf16_t sB[3][256 * 32];

  const int t = threadIdx.x;
  const int w = t >> 6;          // wave 0..7
  const int l = t & 63;
  const int lr = l & 15;         // fragment row (A/B), col (C/D)
  const int hi = l >> 4;         // k-group (operand), row-group (C/D)

  // XCD-aware bijective remap: 2048 blocks = 8 XCDs x 256.
  // XCD x owns bm in [x*32,(x+1)*32) x all 8 bn (bn fastest).
  const int wg = (blockIdx.x & 7) * 256 + (blockIdx.x >> 3);
  const int bm = wg >> 3;        // 0..255  (node-row block, 128 rows)
  const int bn = wg & 7;         // 0..7    (centroid block, 256 cols)

  const int wm = (w >> 2) * 64;  // wave M-offset (0 or 64)
  const int wn = (w & 3) * 64;   // wave N-offset (0,64,128,192)

  floatx4 acc[4][4] = {};

  // ---- staging geometry: thread t handles row t>>2, LDS chunk t&3;
  // pre-swizzled source data chunk = (t&3) ^ ((t>>3)&3)  (== (row>>1)&3,
  // invariant across 64/128-row pass offsets).
  const int scolE = (((t & 3) ^ ((t >> 3) & 3)) << 3);  // element offset
  const bf16_t* gA = A + (size_t)(bm * 128 + (t >> 2)) * D_DIM + scolE;
  const bf16_t* gB = B + (size_t)(bn * 256 + (t >> 2)) * D_DIM + scolE;
  char* ldsW = (char*)nullptr;  // (unused; bases below are wave-uniform)

  // ---- fragment-read geometry: row = {wm|wn} + i*16 + lr -> (row>>1)&3 ==
  // (lr>>1)&3; chunk read = hi ^ that (R4-verified pair).
  const int cOff = ((hi ^ ((lr >> 1) & 3)) << 4);

  // stage one K-tile into ring slot kt%3 (1 A pass + 2 B passes per thread)
  auto stage = [&](int kt) {
    const int sa = (kt % 3) * 8192;
    const int sb = (kt % 3) * 16384;
    gld_lds16(gA + kt * 32, (char*)sA + sa + w * 1024);
    #pragma unroll
    for (int p = 0; p < 2; ++p)
      gld_lds16(gB + (size_t)(p * 128) * D_DIM + kt * 32,
                (char*)sB + sb + p * 8192 + w * 1024);
  };

  auto compute = [&](int kt) {
    const char* aS = (const char*)sA + (kt % 3) * 8192;
    const char* bS = (const char*)sB + (kt % 3) * 16384;
    bf16x8 af[4], bfr[4];
    #pragma unroll
    for (int i = 0; i < 4; ++i)
      af[i] = *(const bf16x8*)(aS + ((wm + i * 16 + lr) << 6) + cOff);
    #pragma unroll
    for (int j = 0; j < 4; ++j)
      bfr[j] = *(const bf16x8*)(bS + ((wn + j * 16 + lr) << 6) + cOff);
    __builtin_amdgcn_s_setprio(1);
    #pragma unroll
    for (int i = 0; i < 4; ++i)
      #pragma unroll
      for (int j = 0; j < 4; ++j)
        acc[i][j] = __builtin_amdgcn_mfma_f32_16x16x32_bf16(
            af[i], bfr[j], acc[i][j], 0, 0, 0);
    __builtin_amdgcn_s_setprio(0);
  };

  // prologue: stage K-tiles 0 and 1 (6 loads/thread in flight)
  stage(0);
  stage(1);

  // main loop: one counted wait + one barrier per K-tile.
  // Entering iter kt: outstanding = stage(kt+1)'s 3 -> vmcnt(3) proves
  // stage(kt) resident. stage(kt+2) overwrites slot (kt-1)%3, whose readers
  // all finished before this barrier (their ds_reads drain before their
  // MFMAs, which precede the barrier; "memory" clobber pins ordering).
  #pragma unroll
  for (int kt = 0; kt < 16; ++kt) {
    if (kt < 15) { S_WAITV3; } else { S_WAITV0; }
    __builtin_amdgcn_s_barrier();
    if (kt + 2 < 16) stage(kt + 2);
    compute(kt);
  }

  // ---- epilogue: C/D layout col = lane&15, row = hi*4 + reg ----
  const int col0 = bn * 256 + wn;
  float c2v[4];
  #pragma unroll
  for (int j = 0; j < 4; ++j) c2v[j] = c2[col0 + j * 16 + lr];

  float colacc[4] = {0.f, 0.f, 0.f, 0.f};
  #pragma unroll
  for (int i = 0; i < 4; ++i) {
    const int rbase = bm * 128 + wm + i * 16 + hi * 4;
    #pragma unroll
    for (int r = 0; r < 4; ++r) {
      const int row = rbase + r;
      const float xv = x2[row];
      const float mk = mask[row];
      float* orow = out_node + (size_t)row * K_CENT + col0 + lr;
      #pragma unroll
      for (int j = 0; j < 4; ++j) {
        float d2 = xv + c2v[j] - 2.0f * acc[i][j][r];
        float dist = sqrtf(fmaxf(d2, 1e-12f));
        float dm = dist * mk;
        orow[j * 16] = dm;
        colacc[j] += dm;
      }
    }
  }

  // reduce column partials within wave (over hi groups)
  #pragma unroll
  for (int j = 0; j < 4; ++j) {
    colacc[j] += __shfl_xor(colacc[j], 16);
    colacc[j] += __shfl_xor(colacc[j], 32);
  }
  // combine the two M-group waves per wn via LDS, one atomic per column
  __syncthreads();                 // safe to reuse sA: K-loop fully consumed
  float* colbuf = (float*)sA;      // 256 floats
  if (w < 4 && l < 16) {
    #pragma unroll
    for (int j = 0; j < 4; ++j) colbuf[wn + j * 16 + l] = colacc[j];
  }
  __syncthreads();
  if (w >= 4 && l < 16) {
    #pragma unroll
    for (int j = 0; j < 4; ++j) colbuf[wn + j * 16 + l] += colacc[j];
  }
  __syncthreads();
  if (t < 256) atomicAdd(&colsum[bn * 256 + t], colbuf[t]);
}

// ---------------- finalize: graph[k] = colsum[k] / masksum ----------------
__global__ void finalize_kernel(const float* __restrict__ colsum,
                                const float* __restrict__ msum,
                                float* __restrict__ out) {
  int k = blockIdx.x * 256 + threadIdx.x;
  out[k] = colsum[k] / msum[0];
}

extern "C" void kernel_launch(void* const* d_in, const int* in_sizes, int n_in,
                              void* d_out, int out_size, void* d_ws, size_t ws_size,
                              hipStream_t stream) {
  const float* node = (const float*)d_in[0];
  const float* mask = (const float*)d_in[1];
  const float* cent = (const float*)d_in[2];
  float* out_graph = (float*)d_out;            // [1, K] first in return order
  float* out_node  = out_graph + K_CENT;       // [1, N, K]

  char* ws = (char*)d_ws;
  size_t off = 0;
  bf16_t* Abf = (bf16_t*)(ws + off); off += (size_t)N_NODES * D_DIM * sizeof(bf16_t);
  bf16_t* Cbf = (bf16_t*)(ws + off); off += (size_t)K_CENT * D_DIM * sizeof(bf16_t);
  float* x2     = (float*)(ws + off); off += (size_t)N_NODES * sizeof(float);
  float* c2     = (float*)(ws + off); off += (size_t)K_CENT * sizeof(float);
  float* colsum = (float*)(ws + off); off += (size_t)K_CENT * sizeof(float);
  float* msum   = (float*)(ws + off); off += sizeof(float);

  hipMemsetAsync(colsum, 0, (K_CENT + 1) * sizeof(float), stream);

  prep_rows_kernel<<<N_NODES / 4, 256, 0, stream>>>(node, Abf, x2);
  prep_rows_kernel<<<K_CENT / 4, 256, 0, stream>>>(cent, Cbf, c2);
  mask_sum_kernel<<<64, 256, 0, stream>>>(mask, msum, N_NODES);
  gemm_dist_kernel<<<2048, 512, 0, stream>>>(
      Abf, Cbf, x2, c2, mask, out_node, colsum);
  finalize_kernel<<<K_CENT / 256, 256, 0, stream>>>(colsum, msum, out_graph);
}